// Round 12
// baseline (102.558 us; speedup 1.0000x reference)
//
#include <hip/hip_runtime.h>

// out[n][o] = sum_{s,i} tanh(slope[s][i][o]*x[n][i] - thres[s][i][o]) * ampli[s][i][o]^2
// N_DATA=128, N_SYN=8, IN_DIM=784, OUT_DIM=128
//
// R3: occupancy bottleneck (16%, 448 blocks) -> split i 4x (1792 blocks).
// R8: kernel <40us but dur flat -> theory: 7.3M f32 atomicAdds onto 16K
//     addresses (448 serialized updates each) dominate. This round: two-phase
//     reduction, ZERO atomics. Phase1 stores partials to d_ws (29.4MB,
//     coalesced). Phase2 (one block per n) sums 448 partials per output and
//     writes d_out directly (also drops the out-memset dispatch).

#define N_DATA  128
#define N_SYN   8
#define IN_DIM  784
#define OUT_DIM 128

#define NTILE   32    // n per block (phase 1)
#define NACC    16    // n per thread
#define ICHUNK  14    // i per block
#define NICHUNK 56    // 784 / 14
#define NTILES  4     // 128 / 32
#define NBLK1   (NTILES * N_SYN * NICHUNK)   // 1792
#define FANIN   (N_SYN * NICHUNK)            // 448 partial tiles per ntile

__global__ __launch_bounds__(256)
void psl_phase1(const float* __restrict__ x,      // [128][784]
                const float* __restrict__ thres,  // [8][784][128]
                const float* __restrict__ slope,  // [8][784][128]
                const float* __restrict__ ampli,  // [8][784][128]
                float* __restrict__ ws)           // [1792][32][128] partials
{
    const int t    = threadIdx.x;
    const int o    = t & 127;       // lane->o, coalesced param loads
    const int nsub = t >> 7;        // 0/1, wave-uniform

    int bid = blockIdx.x;
    const int ic    = bid % NICHUNK; bid /= NICHUNK;
    const int s     = bid % N_SYN;   bid /= N_SYN;
    const int ntile = bid;           // 0..3

    const int i0 = ic * ICHUNK;

    // x tile staged in LDS: [i][n], 14*32*4 = 1792 B
    __shared__ float xs[ICHUNK][NTILE];
    for (int idx = t; idx < ICHUNK * NTILE; idx += 256) {
        const int nl = idx & (NTILE - 1);
        const int il = idx >> 5;
        xs[il][nl] = x[(ntile * NTILE + nl) * IN_DIM + i0 + il];
    }
    __syncthreads();

    float acc[NACC];
#pragma unroll
    for (int k = 0; k < NACC; ++k) acc[k] = 0.f;
    float suma2 = 0.f;

    const float C = 2.8853900817779268f;  // 2*log2(e)
    const int pbase = (s * IN_DIM + i0) * OUT_DIM + o;

#pragma unroll
    for (int il = 0; il < ICHUNK; ++il) {
        const int pidx = pbase + il * OUT_DIM;
        const float sl = slope[pidx];
        const float th = thres[pidx];
        const float am = ampli[pidx];

        const float a2   = am * am;
        suma2 += a2;                       // n-independent term, hoisted
        const float m2a2 = -2.f * a2;
        const float slC  = sl * C;
        const float thC  = th * C;

        // broadcast float4 reads (same address across all lanes -> conflict-free)
        const float4* xrow = reinterpret_cast<const float4*>(&xs[il][nsub * NACC]);
#pragma unroll
        for (int q = 0; q < 4; ++q) {
            const float4 xv = xrow[q];
            {
                float z = __builtin_fmaf(slC, xv.x, -thC);
                float r = __builtin_amdgcn_rcpf(__builtin_amdgcn_exp2f(z) + 1.f);
                acc[4*q+0] = __builtin_fmaf(m2a2, r, acc[4*q+0]);
            }
            {
                float z = __builtin_fmaf(slC, xv.y, -thC);
                float r = __builtin_amdgcn_rcpf(__builtin_amdgcn_exp2f(z) + 1.f);
                acc[4*q+1] = __builtin_fmaf(m2a2, r, acc[4*q+1]);
            }
            {
                float z = __builtin_fmaf(slC, xv.z, -thC);
                float r = __builtin_amdgcn_rcpf(__builtin_amdgcn_exp2f(z) + 1.f);
                acc[4*q+2] = __builtin_fmaf(m2a2, r, acc[4*q+2]);
            }
            {
                float z = __builtin_fmaf(slC, xv.w, -thC);
                float r = __builtin_amdgcn_rcpf(__builtin_amdgcn_exp2f(z) + 1.f);
                acc[4*q+3] = __builtin_fmaf(m2a2, r, acc[4*q+3]);
            }
        }
    }

    // store partials: ws[blockIdx][nsub*16+k][o], coalesced across o
    float* wsb = ws + (size_t)blockIdx.x * (NTILE * OUT_DIM);
#pragma unroll
    for (int k = 0; k < NACC; ++k) {
        wsb[(nsub * NACC + k) * OUT_DIM + o] = acc[k] + suma2;
    }
}

// one block per n: sum 448 partial tiles, write out directly (no atomics)
__global__ __launch_bounds__(256)
void psl_phase2(const float* __restrict__ ws,   // [1792][32][128]
                float* __restrict__ out)        // [128][128]
{
    const int t = threadIdx.x;
    const int o = t & 127;
    const int h = t >> 7;            // 0/1: split the 448-sum in half
    const int n = blockIdx.x;        // 0..127
    const int ntile = n >> 5;
    const int nl    = n & 31;

    __shared__ float red[OUT_DIM];

    // term j in [0,448): address = ((ntile*448 + j)*32 + nl)*128 + o
    const float* p = ws + (((size_t)(ntile * FANIN + h * (FANIN / 2)) * NTILE + nl) * OUT_DIM) + o;
    const size_t stride = (size_t)NTILE * OUT_DIM;  // 4096 floats between j's

    float sum = 0.f;
#pragma unroll 8
    for (int m = 0; m < FANIN / 2; ++m) {
        sum += p[m * stride];
    }

    if (h == 1) red[o] = sum;
    __syncthreads();
    if (h == 0) out[n * OUT_DIM + o] = sum + red[o];
}

extern "C" void kernel_launch(void* const* d_in, const int* in_sizes, int n_in,
                              void* d_out, int out_size, void* d_ws, size_t ws_size,
                              hipStream_t stream) {
    const float* x     = (const float*)d_in[0];
    const float* thres = (const float*)d_in[1];
    const float* slope = (const float*)d_in[2];
    const float* ampli = (const float*)d_in[3];
    float* out = (float*)d_out;
    float* ws  = (float*)d_ws;   // uses 1792*32*128*4 = 29.36 MB

    psl_phase1<<<NBLK1, 256, 0, stream>>>(x, thres, slope, ampli, ws);
    psl_phase2<<<N_DATA, 256, 0, stream>>>(ws, out);
}

// Round 13
// 98.017 us; speedup vs baseline: 1.0463x; 1.0463x over previous
//
#include <hip/hip_runtime.h>

// out[n][o] = sum_{s,i} tanh(slope[s][i][o]*x[n][i] - thres[s][i][o]) * ampli[s][i][o]^2
// N_DATA=128, N_SYN=8, IN_DIM=784, OUT_DIM=128
//
// R3:  occupancy bottleneck (16%, 448 blocks) -> split i 4x (1792 blocks).
// R8:  atomic-fanin theory -> R12 two-phase refuted it (dur flat 101->102.6).
// R12: decomposition: phase1+phase2 ~= 45us; phase1 floor ~10.5-15us (trans-
//      unit bound) => phase2 ~= 25-30us: 128 blocks x 4 waves, 224 scalar
//      strided loads/thread, latency-bound gather.
// R13: rebuild phase2 only: 1024 thr/block, float4 gather (14 independent
//      16B loads/thread, fully unrolled), 16KB LDS combine. phase1 untouched.

#define N_DATA  128
#define N_SYN   8
#define IN_DIM  784
#define OUT_DIM 128

#define NTILE   32    // n per block (phase 1)
#define NACC    16    // n per thread
#define ICHUNK  14    // i per block
#define NICHUNK 56    // 784 / 14
#define NTILES  4     // 128 / 32
#define NBLK1   (NTILES * N_SYN * NICHUNK)   // 1792
#define FANIN   (N_SYN * NICHUNK)            // 448 partial tiles per ntile

__global__ __launch_bounds__(256)
void psl_phase1(const float* __restrict__ x,      // [128][784]
                const float* __restrict__ thres,  // [8][784][128]
                const float* __restrict__ slope,  // [8][784][128]
                const float* __restrict__ ampli,  // [8][784][128]
                float* __restrict__ ws)           // [1792][32][128] partials
{
    const int t    = threadIdx.x;
    const int o    = t & 127;       // lane->o, coalesced param loads
    const int nsub = t >> 7;        // 0/1, wave-uniform

    int bid = blockIdx.x;
    const int ic    = bid % NICHUNK; bid /= NICHUNK;
    const int s     = bid % N_SYN;   bid /= N_SYN;
    const int ntile = bid;           // 0..3

    const int i0 = ic * ICHUNK;

    // x tile staged in LDS: [i][n], 14*32*4 = 1792 B
    __shared__ float xs[ICHUNK][NTILE];
    for (int idx = t; idx < ICHUNK * NTILE; idx += 256) {
        const int nl = idx & (NTILE - 1);
        const int il = idx >> 5;
        xs[il][nl] = x[(ntile * NTILE + nl) * IN_DIM + i0 + il];
    }
    __syncthreads();

    float acc[NACC];
#pragma unroll
    for (int k = 0; k < NACC; ++k) acc[k] = 0.f;
    float suma2 = 0.f;

    const float C = 2.8853900817779268f;  // 2*log2(e)
    const int pbase = (s * IN_DIM + i0) * OUT_DIM + o;

#pragma unroll
    for (int il = 0; il < ICHUNK; ++il) {
        const int pidx = pbase + il * OUT_DIM;
        const float sl = slope[pidx];
        const float th = thres[pidx];
        const float am = ampli[pidx];

        const float a2   = am * am;
        suma2 += a2;                       // n-independent term, hoisted
        const float m2a2 = -2.f * a2;
        const float slC  = sl * C;
        const float thC  = th * C;

        // broadcast float4 reads (same address across all lanes -> conflict-free)
        const float4* xrow = reinterpret_cast<const float4*>(&xs[il][nsub * NACC]);
#pragma unroll
        for (int q = 0; q < 4; ++q) {
            const float4 xv = xrow[q];
            {
                float z = __builtin_fmaf(slC, xv.x, -thC);
                float r = __builtin_amdgcn_rcpf(__builtin_amdgcn_exp2f(z) + 1.f);
                acc[4*q+0] = __builtin_fmaf(m2a2, r, acc[4*q+0]);
            }
            {
                float z = __builtin_fmaf(slC, xv.y, -thC);
                float r = __builtin_amdgcn_rcpf(__builtin_amdgcn_exp2f(z) + 1.f);
                acc[4*q+1] = __builtin_fmaf(m2a2, r, acc[4*q+1]);
            }
            {
                float z = __builtin_fmaf(slC, xv.z, -thC);
                float r = __builtin_amdgcn_rcpf(__builtin_amdgcn_exp2f(z) + 1.f);
                acc[4*q+2] = __builtin_fmaf(m2a2, r, acc[4*q+2]);
            }
            {
                float z = __builtin_fmaf(slC, xv.w, -thC);
                float r = __builtin_amdgcn_rcpf(__builtin_amdgcn_exp2f(z) + 1.f);
                acc[4*q+3] = __builtin_fmaf(m2a2, r, acc[4*q+3]);
            }
        }
    }

    // store partials: ws[blockIdx][nsub*16+k][o], coalesced across o
    float* wsb = ws + (size_t)blockIdx.x * (NTILE * OUT_DIM);
#pragma unroll
    for (int k = 0; k < NACC; ++k) {
        wsb[(nsub * NACC + k) * OUT_DIM + o] = acc[k] + suma2;
    }
}

// one block per n, 1024 threads: 32 j-groups x 32 float4-columns.
// thread (g,o4) sums j = g + 32*m (m=0..13) -> 14 independent float4 loads,
// then LDS combine across the 32 groups. No atomics.
__global__ __launch_bounds__(1024)
void psl_phase2(const float* __restrict__ ws,   // [1792][32][128]
                float* __restrict__ out)        // [128][128]
{
    const int t  = threadIdx.x;      // 0..1023
    const int g  = t >> 5;           // 0..31 : j-group
    const int o4 = t & 31;           // float4 column (o = o4*4..o4*4+3)
    const int n  = blockIdx.x;       // 0..127
    const int ntile = n >> 5;
    const int nl    = n & 31;

    __shared__ float red[32][OUT_DIM];   // 16 KB

    // tile (ntile, j, nl) row base: ((ntile*448 + j)*32 + nl)*128 floats
    const float4* base = reinterpret_cast<const float4*>(
        ws + (((size_t)ntile * FANIN * NTILE + nl) * OUT_DIM)) + o4;
    const size_t jstep = (size_t)NTILE * OUT_DIM / 4;   // 1024 float4 per j

    float4 acc = make_float4(0.f, 0.f, 0.f, 0.f);
#pragma unroll
    for (int m = 0; m < FANIN / 32; ++m) {              // 14 iterations
        const float4 v = base[(size_t)(g + 32 * m) * jstep];
        acc.x += v.x; acc.y += v.y; acc.z += v.z; acc.w += v.w;
    }
    *reinterpret_cast<float4*>(&red[g][o4 * 4]) = acc;
    __syncthreads();

    if (t < OUT_DIM) {
        float s = 0.f;
#pragma unroll
        for (int g2 = 0; g2 < 32; ++g2) s += red[g2][t];
        out[n * OUT_DIM + t] = s;
    }
}

extern "C" void kernel_launch(void* const* d_in, const int* in_sizes, int n_in,
                              void* d_out, int out_size, void* d_ws, size_t ws_size,
                              hipStream_t stream) {
    const float* x     = (const float*)d_in[0];
    const float* thres = (const float*)d_in[1];
    const float* slope = (const float*)d_in[2];
    const float* ampli = (const float*)d_in[3];
    float* out = (float*)d_out;
    float* ws  = (float*)d_ws;   // uses 1792*32*128*4 = 29.36 MB

    psl_phase1<<<NBLK1, 256, 0, stream>>>(x, thres, slope, ampli, ws);
    psl_phase2<<<N_DATA, 1024, 0, stream>>>(ws, out);
}